// Round 1
// baseline (228.268 us; speedup 1.0000x reference)
//
#include <hip/hip_runtime.h>
#include <hip/hip_bf16.h>
#include <stdint.h>

#define DM   1024
#define SEQ  2048
#define BATCH 4
#define NH   16
#define DK   64

typedef __attribute__((ext_vector_type(8))) __bf16 bf16x8;
typedef __attribute__((ext_vector_type(4))) float f32x4;
typedef __attribute__((ext_vector_type(4))) unsigned short ushort4_t;

typedef __attribute__((address_space(1))) const unsigned int GU32;
typedef __attribute__((address_space(3))) unsigned int LU32;

__device__ inline void gl_lds16(const void* g, void* l) {
  __builtin_amdgcn_global_load_lds((GU32*)g, (LU32*)l, 16, 0, 0);
}

__device__ inline f32x4 mfma16(bf16x8 a, bf16x8 b, f32x4 c) {
  return __builtin_amdgcn_mfma_f32_16x16x32_bf16(a, b, c, 0, 0, 0);
}

__device__ inline unsigned short f2bf(float f) {
  unsigned u = __float_as_uint(f);
  u += 0x7fffu + ((u >> 16) & 1u);
  return (unsigned short)(u >> 16);
}

// ---------------- prep: fp32 -> bf16 conversions + rope table ----------------
__global__ void prep_kernel(const float* __restrict__ x,
                            const float* __restrict__ wq, const float* __restrict__ wk,
                            const float* __restrict__ wv, const float* __restrict__ wo,
                            const int* __restrict__ tp,
                            unsigned short* __restrict__ xbf,
                            unsigned short* __restrict__ wbf,   // 4 weights contiguous
                            float2* __restrict__ tab)
{
  const int NX4 = (BATCH*SEQ*DM)/4;   // 2097152
  const int NW4 = (DM*DM)/4;          // 262144 = 2^18
  int idx = blockIdx.x*256 + threadIdx.x;
  if (idx < NX4) {
    float4 v = ((const float4*)x)[idx];
    ushort4_t o; o[0]=f2bf(v.x); o[1]=f2bf(v.y); o[2]=f2bf(v.z); o[3]=f2bf(v.w);
    ((ushort4_t*)xbf)[idx] = o;
  } else if (idx < NX4 + 4*NW4) {
    int t = idx - NX4;
    int wsel = t >> 18;
    int off = t & (NW4-1);
    const float* src = (wsel==0) ? wq : (wsel==1) ? wk : (wsel==2) ? wv : wo;
    float4 v = ((const float4*)src)[off];
    ushort4_t o; o[0]=f2bf(v.x); o[1]=f2bf(v.y); o[2]=f2bf(v.z); o[3]=f2bf(v.w);
    ((ushort4_t*)wbf)[wsel*NW4 + off] = o;
  } else {
    int t = idx - NX4 - 4*NW4;
    if (t < SEQ*32) {
      int s = t >> 5, i = t & 31;
      // inv_freq = 10000^(-i/32); log2(10000) = 13.287712379549449
      float invf = exp2f(-(float)i * (13.287712379549449f/32.0f));
      float ang = (float)tp[s] * invf;
      float sn, cs; sincosf(ang, &sn, &cs);
      tab[t] = make_float2(cs, sn);
    }
  }
}

// ---------------- GEMM: C = A(rows x K) * B(rows x K)^T, bf16, fp32 acc ------
// MODE 0: C[m][n] -> rope -> q/k bf16 [b,h,s,d]
// MODE 1: A=W, B=X -> C[n][m] -> v^T bf16 [b,h,d,s]
// MODE 2: C[m][n] -> fp32 d_out
template<int MODE>
__global__ __launch_bounds__(256, 2)
void gemm_bt(const unsigned short* __restrict__ A,
             const unsigned short* __restrict__ Bm,
             unsigned short* __restrict__ obf,
             float* __restrict__ ofp,
             const float2* __restrict__ tab)
{
  __shared__ unsigned short As[128*32];
  __shared__ unsigned short Bs[128*32];
  const int tid = threadIdx.x;
  const int a0 = blockIdx.y*128, b0r = blockIdx.x*128;
  const int w = tid>>6, lane = tid&63, ln = lane&15, g = lane>>4;
  const int wm = (w>>1)*64, wn = (w&1)*64;

  f32x4 acc[4][4];
  #pragma unroll
  for (int i=0;i<4;i++)
    #pragma unroll
    for (int j=0;j<4;j++) acc[i][j] = (f32x4){0.f,0.f,0.f,0.f};

  const int bofs = tid*16;        // byte offset within 4KB half-tile
  const int row0 = bofs>>6;       // 64B per LDS row (32 bf16)
  const int colB = bofs&63;
  const char* aB1 = (const char*)(A + (size_t)(a0+row0)*DM);
  const char* aB2 = (const char*)(A + (size_t)(a0+64+row0)*DM);
  const char* bB1 = (const char*)(Bm + (size_t)(b0r+row0)*DM);
  const char* bB2 = (const char*)(Bm + (size_t)(b0r+64+row0)*DM);

  for (int kt = 0; kt < 32; ++kt) {
    const int kB = kt*64 + colB;   // byte offset into row
    gl_lds16(aB1 + kB, (char*)As + bofs);
    gl_lds16(aB2 + kB, (char*)As + 4096 + bofs);
    gl_lds16(bB1 + kB, (char*)Bs + bofs);
    gl_lds16(bB2 + kB, (char*)Bs + 4096 + bofs);
    __syncthreads();
    bf16x8 af[4], bfv[4];
    #pragma unroll
    for (int i=0;i<4;i++) af[i]  = *(const bf16x8*)&As[(wm + i*16 + ln)*32 + g*8];
    #pragma unroll
    for (int i=0;i<4;i++) bfv[i] = *(const bf16x8*)&Bs[(wn + i*16 + ln)*32 + g*8];
    #pragma unroll
    for (int i=0;i<4;i++)
      #pragma unroll
      for (int jn=0;jn<4;jn++)
        acc[i][jn] = mfma16(af[i], bfv[jn], acc[i][jn]);
    __syncthreads();
  }

  if (MODE == 2) {
    #pragma unroll
    for (int i=0;i<4;i++) {
      int m = a0 + wm + i*16 + g*4;
      #pragma unroll
      for (int jn=0;jn<4;jn++) {
        int n = b0r + wn + jn*16 + ln;
        #pragma unroll
        for (int j=0;j<4;j++)
          ofp[(size_t)(m+j)*DM + n] = acc[i][jn][j];
      }
    }
  } else if (MODE == 0) {
    // rope + write [b,h,s,d] bf16
    #pragma unroll
    for (int jn=0;jn<4;jn++) {
      int n = b0r + wn + jn*16 + ln;      // 0..1023 model col
      int h = n>>6, d = n&63, di = d>>1, par = d&1;
      #pragma unroll
      for (int i=0;i<4;i++) {
        #pragma unroll
        for (int j=0;j<4;j++) {
          int m = a0 + wm + i*16 + g*4 + j;
          int bb = m>>11, s = m&2047;
          float v = acc[i][jn][j];
          float pv = __shfl_xor(v, 1);    // partner dim (d^1), same (i,jn,j)
          float2 cssn = tab[s*32 + di];
          float r = par ? (v*cssn.x + pv*cssn.y) : (v*cssn.x - pv*cssn.y);
          obf[((size_t)(bb*NH + h)*SEQ + s)*DK + d] = f2bf(r);
        }
      }
    }
  } else {
    // MODE 1: C[r=n][c=m] -> v^T [b,h,d,s]
    #pragma unroll
    for (int i=0;i<4;i++) {
      #pragma unroll
      for (int j=0;j<4;j++) {
        int n = a0 + wm + i*16 + g*4 + j;  // W row = model col
        int h = n>>6, d = n&63;
        #pragma unroll
        for (int jn=0;jn<4;jn++) {
          int m = b0r + wn + jn*16 + ln;   // 16 contiguous s per (i,j)
          int bb = m>>11, s = m&2047;
          obf[((size_t)(bb*NH + h)*DK + d)*SEQ + s] = f2bf(acc[i][jn][j]);
        }
      }
    }
  }
}

// ---------------- flash attention ----------------
// block = (head bh, q-block of 64 rows), 4 waves x 16 q-rows each.
// scores via swapped mfma(K,Q): lane&15 = q row -> row softmax by shfl_xor(16,32)
__global__ __launch_bounds__(256, 2)
void attn_fa(const unsigned short* __restrict__ qbf,
             const unsigned short* __restrict__ kbf,
             const unsigned short* __restrict__ vtg,
             unsigned short* __restrict__ attnbf)
{
  __shared__ unsigned short Kt[64][72];      // [kv][d], +16B pad
  __shared__ unsigned short Vt[64][72];      // [d][kv], +16B pad
  __shared__ unsigned short Pl[4][16][72];   // per-wave P [q][kv]
  const int bh = blockIdx.x, qb = blockIdx.y;
  const int tid = threadIdx.x, w = tid>>6, lane = tid&63, ln = lane&15, g = lane>>4;
  const int q0 = qb*64 + w*16;

  const unsigned short* qrow = qbf + ((size_t)bh*SEQ + q0 + ln)*DK;
  bf16x8 qf0 = *(const bf16x8*)(qrow + g*8);
  bf16x8 qf1 = *(const bf16x8*)(qrow + 32 + g*8);

  f32x4 o[4];
  #pragma unroll
  for (int f=0;f<4;f++) o[f] = (f32x4){0.f,0.f,0.f,0.f};
  float m_run = -INFINITY, l_run = 0.f;

  const int sr = tid>>2, sc16 = (tid&3)*16;
  const unsigned short* ksrc = kbf + ((size_t)bh*SEQ + sr)*DK + sc16;
  const unsigned short* vsrc = vtg + ((size_t)bh*DK + sr)*SEQ + sc16;
  const float SCL = 0.125f * 1.44269504089f;   // 1/sqrt(64) * log2(e)
  const int qg = q0 + ln;

  for (int t = 0; t <= qb; ++t) {
    const int kv0 = t*64;
    __syncthreads();
    { // stage K [64][64] and V^T [64][64]
      bf16x8 k0v = *(const bf16x8*)(ksrc + (size_t)kv0*DK);
      bf16x8 k1v = *(const bf16x8*)(ksrc + (size_t)kv0*DK + 8);
      bf16x8 v0v = *(const bf16x8*)(vsrc + kv0);
      bf16x8 v1v = *(const bf16x8*)(vsrc + kv0 + 8);
      *(bf16x8*)&Kt[sr][sc16]   = k0v;
      *(bf16x8*)&Kt[sr][sc16+8] = k1v;
      *(bf16x8*)&Vt[sr][sc16]   = v0v;
      *(bf16x8*)&Vt[sr][sc16+8] = v1v;
    }
    __syncthreads();

    // scores: S^T tile = mfma(K, Q): lane holds S[q=ln][kv=16*kvf+4g+j]
    f32x4 sa[4];
    #pragma unroll
    for (int kvf=0;kvf<4;kvf++) {
      f32x4 z = (f32x4){0.f,0.f,0.f,0.f};
      bf16x8 kf0 = *(const bf16x8*)&Kt[kvf*16 + ln][g*8];
      bf16x8 kf1 = *(const bf16x8*)&Kt[kvf*16 + ln][32 + g*8];
      z = mfma16(kf0, qf0, z);
      z = mfma16(kf1, qf1, z);
      sa[kvf] = z;
    }

    float sc[4][4];
    float lmax = -INFINITY;
    if (t == qb) {
      #pragma unroll
      for (int kvf=0;kvf<4;kvf++)
        #pragma unroll
        for (int j=0;j<4;j++) {
          int kv = kv0 + kvf*16 + g*4 + j;
          float v = (kv <= qg) ? sa[kvf][j]*SCL : -1e30f;
          sc[kvf][j] = v; lmax = fmaxf(lmax, v);
        }
    } else {
      #pragma unroll
      for (int kvf=0;kvf<4;kvf++)
        #pragma unroll
        for (int j=0;j<4;j++) {
          float v = sa[kvf][j]*SCL;
          sc[kvf][j] = v; lmax = fmaxf(lmax, v);
        }
    }
    lmax = fmaxf(lmax, __shfl_xor(lmax, 16));
    lmax = fmaxf(lmax, __shfl_xor(lmax, 32));
    float mnew = fmaxf(m_run, lmax);
    float corr = exp2f(m_run - mnew);   // first tile: exp2(-inf)=0

    float lsum = 0.f;
    #pragma unroll
    for (int kvf=0;kvf<4;kvf++) {
      ushort4_t pk;
      #pragma unroll
      for (int j=0;j<4;j++) {
        float p = exp2f(sc[kvf][j] - mnew);
        lsum += p;
        pk[j] = f2bf(p);
      }
      *(ushort4_t*)&Pl[w][ln][kvf*16 + g*4] = pk;
    }
    lsum += __shfl_xor(lsum, 16);
    lsum += __shfl_xor(lsum, 32);
    l_run = l_run*corr + lsum;
    m_run = mnew;

    // rescale O (O-frag rows are q=g*4+j; softmax state lives at lane q)
    #pragma unroll
    for (int j=0;j<4;j++) {
      float cj = __shfl(corr, g*4 + j);
      #pragma unroll
      for (int f=0;f<4;f++) o[f][j] *= cj;
    }

    asm volatile("s_waitcnt lgkmcnt(0)" ::: "memory");  // P writes -> reads

    #pragma unroll
    for (int c=0;c<2;c++) {
      bf16x8 pf = *(const bf16x8*)&Pl[w][ln][c*32 + g*8];
      #pragma unroll
      for (int f=0;f<4;f++) {
        bf16x8 vf = *(const bf16x8*)&Vt[f*16 + ln][c*32 + g*8];
        o[f] = mfma16(pf, vf, o[f]);
      }
    }
  }

  const int bb = bh>>4, h = bh&15;
  #pragma unroll
  for (int j=0;j<4;j++) {
    float linv = 1.0f / __shfl(l_run, g*4 + j);
    int s = q0 + g*4 + j;
    #pragma unroll
    for (int f=0;f<4;f++)
      attnbf[((size_t)bb*SEQ + s)*DM + h*DK + f*16 + ln] = f2bf(o[f][j]*linv);
  }
}

// ---------------- launch ----------------
extern "C" void kernel_launch(void* const* d_in, const int* in_sizes, int n_in,
                              void* d_out, int out_size, void* d_ws, size_t ws_size,
                              hipStream_t stream)
{
  const float* x  = (const float*)d_in[0];
  const float* wq = (const float*)d_in[1];
  const float* wk = (const float*)d_in[2];
  const float* wv = (const float*)d_in[3];
  const float* wo = (const float*)d_in[4];
  const int*   tp = (const int*)d_in[5];

  const size_t XB = (size_t)BATCH*SEQ*DM*2;   // 16 MiB bf16 activation buffer
  const size_t WB = (size_t)DM*DM*2;          // 2 MiB bf16 weight
  const int    NW = DM*DM;

  char* ws = (char*)d_ws;
  unsigned short* xbf = (unsigned short*)(ws);
  unsigned short* qbf = (unsigned short*)(ws + XB);
  unsigned short* kbf = (unsigned short*)(ws + 2*XB);
  unsigned short* vt  = (unsigned short*)(ws + 3*XB);
  unsigned short* abf = (unsigned short*)(ws + 4*XB);
  unsigned short* wbf = (unsigned short*)(ws + 5*XB);
  float2* tab = (float2*)(ws + 5*XB + 4*WB);

  prep_kernel<<<12544, 256, 0, stream>>>(x, wq, wk, wv, wo, tp, xbf, wbf, tab);

  // Q and K projections (rope fused)
  gemm_bt<0><<<dim3(8,64), 256, 0, stream>>>(xbf, wbf,        qbf, nullptr, tab);
  gemm_bt<0><<<dim3(8,64), 256, 0, stream>>>(xbf, wbf + NW,   kbf, nullptr, tab);
  // V projection, swapped -> v^T
  gemm_bt<1><<<dim3(64,8), 256, 0, stream>>>(wbf + 2*NW, xbf, vt,  nullptr, nullptr);
  // attention
  attn_fa<<<dim3(64,32), 256, 0, stream>>>(qbf, kbf, vt, abf);
  // output projection -> fp32 d_out
  gemm_bt<2><<<dim3(8,64), 256, 0, stream>>>(abf, wbf + 3*NW, nullptr, (float*)d_out, nullptr);
}

// Round 2
// 204.505 us; speedup vs baseline: 1.1162x; 1.1162x over previous
//
#include <hip/hip_runtime.h>
#include <hip/hip_bf16.h>
#include <stdint.h>

#define DM   1024
#define SEQ  2048
#define BATCH 4
#define NH   16
#define DK   64

typedef __attribute__((ext_vector_type(8))) __bf16 bf16x8;
typedef __attribute__((ext_vector_type(4))) float f32x4;
typedef __attribute__((ext_vector_type(4))) unsigned short ushort4_t;

typedef __attribute__((address_space(1))) const unsigned int GU32;
typedef __attribute__((address_space(3))) unsigned int LU32;

__device__ inline void gl_lds16(const void* g, void* l) {
  __builtin_amdgcn_global_load_lds((GU32*)g, (LU32*)l, 16, 0, 0);
}

__device__ inline f32x4 mfma16(bf16x8 a, bf16x8 b, f32x4 c) {
  return __builtin_amdgcn_mfma_f32_16x16x32_bf16(a, b, c, 0, 0, 0);
}

__device__ inline unsigned short f2bf(float f) {
  unsigned u = __float_as_uint(f);
  u += 0x7fffu + ((u >> 16) & 1u);
  return (unsigned short)(u >> 16);
}

__device__ inline unsigned cvt_pk_bf16(float a, float b) {
  unsigned r;
  asm("v_cvt_pk_bf16_f32 %0, %1, %2" : "=v"(r) : "v"(a), "v"(b));
  return r;  // lo = bf16(a), hi = bf16(b)
}

// ---------------- prep: fp32 -> bf16 conversions + rope table ----------------
__global__ void prep_kernel(const float* __restrict__ x,
                            const float* __restrict__ wq, const float* __restrict__ wk,
                            const float* __restrict__ wv, const float* __restrict__ wo,
                            const int* __restrict__ tp,
                            unsigned short* __restrict__ xbf,
                            unsigned short* __restrict__ wbf,   // 4 weights contiguous
                            float2* __restrict__ tab)
{
  const int NX4 = (BATCH*SEQ*DM)/4;   // 2097152
  const int NW4 = (DM*DM)/4;          // 262144 = 2^18
  int idx = blockIdx.x*256 + threadIdx.x;
  if (idx < NX4) {
    float4 v = ((const float4*)x)[idx];
    ushort4_t o; o[0]=f2bf(v.x); o[1]=f2bf(v.y); o[2]=f2bf(v.z); o[3]=f2bf(v.w);
    ((ushort4_t*)xbf)[idx] = o;
  } else if (idx < NX4 + 4*NW4) {
    int t = idx - NX4;
    int wsel = t >> 18;
    int off = t & (NW4-1);
    const float* src = (wsel==0) ? wq : (wsel==1) ? wk : (wsel==2) ? wv : wo;
    float4 v = ((const float4*)src)[off];
    ushort4_t o; o[0]=f2bf(v.x); o[1]=f2bf(v.y); o[2]=f2bf(v.z); o[3]=f2bf(v.w);
    ((ushort4_t*)wbf)[wsel*NW4 + off] = o;
  } else {
    int t = idx - NX4 - 4*NW4;
    if (t < SEQ*32) {
      int s = t >> 5, i = t & 31;
      // inv_freq = 10000^(-i/32); log2(10000) = 13.287712379549449
      float invf = exp2f(-(float)i * (13.287712379549449f/32.0f));
      float ang = (float)tp[s] * invf;
      float sn, cs; sincosf(ang, &sn, &cs);
      tab[t] = make_float2(cs, sn);
    }
  }
}

// ---------------- fused QKV projection GEMM -----------------------------------
// C = X(8192x1024) * W^T for W in {Wq, Wk, Wv} selected by blockIdx.x>>3.
// sel 0: rope + pre-scale (1/8 * log2e) -> qbf [b,h,s,d]
// sel 1: rope -> kbf [b,h,s,d]
// sel 2: transpose -> vt [b,h,d,s]
__global__ __launch_bounds__(256, 2)
void gemm_qkv(const unsigned short* __restrict__ A,
              const unsigned short* __restrict__ Wall,
              unsigned short* __restrict__ qbf,
              unsigned short* __restrict__ kbf,
              unsigned short* __restrict__ vt,
              const float2* __restrict__ tab)
{
  __shared__ unsigned short As[128*32];
  __shared__ unsigned short Bs[128*32];
  const int tid = threadIdx.x;
  const int bx = blockIdx.x, sel = bx>>3;
  const unsigned short* Bm = Wall + (size_t)sel*DM*DM;
  const int a0 = blockIdx.y*128, b0r = (bx&7)*128;
  const int w = tid>>6, lane = tid&63, ln = lane&15, g = lane>>4;
  const int wm = (w>>1)*64, wn = (w&1)*64;

  f32x4 acc[4][4];
  #pragma unroll
  for (int i=0;i<4;i++)
    #pragma unroll
    for (int j=0;j<4;j++) acc[i][j] = (f32x4){0.f,0.f,0.f,0.f};

  const int bofs = tid*16;        // byte offset within 4KB half-tile
  const int row0 = bofs>>6;       // 64B per LDS row (32 bf16)
  const int colB = bofs&63;
  const char* aB1 = (const char*)(A + (size_t)(a0+row0)*DM);
  const char* aB2 = (const char*)(A + (size_t)(a0+64+row0)*DM);
  const char* bB1 = (const char*)(Bm + (size_t)(b0r+row0)*DM);
  const char* bB2 = (const char*)(Bm + (size_t)(b0r+64+row0)*DM);

  for (int kt = 0; kt < 32; ++kt) {
    const int kB = kt*64 + colB;   // byte offset into row
    gl_lds16(aB1 + kB, (char*)As + bofs);
    gl_lds16(aB2 + kB, (char*)As + 4096 + bofs);
    gl_lds16(bB1 + kB, (char*)Bs + bofs);
    gl_lds16(bB2 + kB, (char*)Bs + 4096 + bofs);
    __syncthreads();
    bf16x8 af[4], bfv[4];
    #pragma unroll
    for (int i=0;i<4;i++) af[i]  = *(const bf16x8*)&As[(wm + i*16 + ln)*32 + g*8];
    #pragma unroll
    for (int i=0;i<4;i++) bfv[i] = *(const bf16x8*)&Bs[(wn + i*16 + ln)*32 + g*8];
    #pragma unroll
    for (int i=0;i<4;i++)
      #pragma unroll
      for (int jn=0;jn<4;jn++)
        acc[i][jn] = mfma16(af[i], bfv[jn], acc[i][jn]);
    __syncthreads();
  }

  if (sel == 2) {
    // transpose -> v^T [b,h,d,s]; 4 consecutive s per lane -> 8B stores
    #pragma unroll
    for (int i=0;i<4;i++) {
      int m0 = a0 + wm + i*16 + g*4;
      int bb = m0>>11, s0 = m0&2047;
      #pragma unroll
      for (int jn=0;jn<4;jn++) {
        int n = b0r + wn + jn*16 + ln;
        int h = n>>6, d = n&63;
        ushort4_t o4;
        #pragma unroll
        for (int j=0;j<4;j++) o4[j] = f2bf(acc[i][jn][j]);
        *(ushort4_t*)&vt[(((size_t)bb*NH + h)*DK + d)*SEQ + s0] = o4;
      }
    }
  } else {
    unsigned short* dst = sel ? kbf : qbf;
    const float qs = sel ? 1.0f : 0.1803368802f;   // 1/8 * log2(e) folded into Q
    #pragma unroll
    for (int jn=0;jn<4;jn++) {
      int n = b0r + wn + jn*16 + ln;      // 0..1023 model col
      int h = n>>6, d = n&63, di = d>>1, par = d&1;
      #pragma unroll
      for (int i=0;i<4;i++) {
        #pragma unroll
        for (int j=0;j<4;j++) {
          int m = a0 + wm + i*16 + g*4 + j;
          int bb = m>>11, s = m&2047;
          float v = acc[i][jn][j];
          float pv = __shfl_xor(v, 1);    // partner dim (d^1), same (i,jn,j)
          float2 cssn = tab[s*32 + di];
          float r = par ? (v*cssn.x + pv*cssn.y) : (v*cssn.x - pv*cssn.y);
          dst[((size_t)(bb*NH + h)*SEQ + s)*DK + d] = f2bf(r*qs);
        }
      }
    }
  }
}

// ---------------- O projection GEMM -> fp32 d_out ------------------------------
__global__ __launch_bounds__(256, 2)
void gemm_ot(const unsigned short* __restrict__ A,
             const unsigned short* __restrict__ Bm,
             float* __restrict__ ofp)
{
  __shared__ unsigned short As[128*32];
  __shared__ unsigned short Bs[128*32];
  const int tid = threadIdx.x;
  const int a0 = blockIdx.y*128, b0r = blockIdx.x*128;
  const int w = tid>>6, lane = tid&63, ln = lane&15, g = lane>>4;
  const int wm = (w>>1)*64, wn = (w&1)*64;

  f32x4 acc[4][4];
  #pragma unroll
  for (int i=0;i<4;i++)
    #pragma unroll
    for (int j=0;j<4;j++) acc[i][j] = (f32x4){0.f,0.f,0.f,0.f};

  const int bofs = tid*16;
  const int row0 = bofs>>6;
  const int colB = bofs&63;
  const char* aB1 = (const char*)(A + (size_t)(a0+row0)*DM);
  const char* aB2 = (const char*)(A + (size_t)(a0+64+row0)*DM);
  const char* bB1 = (const char*)(Bm + (size_t)(b0r+row0)*DM);
  const char* bB2 = (const char*)(Bm + (size_t)(b0r+64+row0)*DM);

  for (int kt = 0; kt < 32; ++kt) {
    const int kB = kt*64 + colB;
    gl_lds16(aB1 + kB, (char*)As + bofs);
    gl_lds16(aB2 + kB, (char*)As + 4096 + bofs);
    gl_lds16(bB1 + kB, (char*)Bs + bofs);
    gl_lds16(bB2 + kB, (char*)Bs + 4096 + bofs);
    __syncthreads();
    bf16x8 af[4], bfv[4];
    #pragma unroll
    for (int i=0;i<4;i++) af[i]  = *(const bf16x8*)&As[(wm + i*16 + ln)*32 + g*8];
    #pragma unroll
    for (int i=0;i<4;i++) bfv[i] = *(const bf16x8*)&Bs[(wn + i*16 + ln)*32 + g*8];
    #pragma unroll
    for (int i=0;i<4;i++)
      #pragma unroll
      for (int jn=0;jn<4;jn++)
        acc[i][jn] = mfma16(af[i], bfv[jn], acc[i][jn]);
    __syncthreads();
  }

  #pragma unroll
  for (int i=0;i<4;i++) {
    int m = a0 + wm + i*16 + g*4;
    #pragma unroll
    for (int jn=0;jn<4;jn++) {
      int n = b0r + wn + jn*16 + ln;
      #pragma unroll
      for (int j=0;j<4;j++)
        ofp[(size_t)(m+j)*DM + n] = acc[i][jn][j];
    }
  }
}

// ---------------- flash attention ----------------
// block = (head bh, q-block of 64 rows), 4 waves x 16 q-rows each.
// scores via swapped mfma(K,Q): lane&15 = q row -> row softmax by shfl_xor(16,32)
// Q is pre-scaled by 1/8*log2e, so scores are already in exp2 domain.
__global__ __launch_bounds__(256, 2)
void attn_fa(const unsigned short* __restrict__ qbf,
             const unsigned short* __restrict__ kbf,
             const unsigned short* __restrict__ vtg,
             unsigned short* __restrict__ attnbf)
{
  __shared__ unsigned short Kt[64][72];      // [kv][d], +16B pad
  __shared__ unsigned short Vt[64][72];      // [d][kv], +16B pad
  __shared__ unsigned short Pl[4][16][72];   // per-wave P [q][kv]
  const int bh = blockIdx.x, qb = 31 - blockIdx.y;   // heavy blocks first
  const int tid = threadIdx.x, w = tid>>6, lane = tid&63, ln = lane&15, g = lane>>4;
  const int q0 = qb*64 + w*16;

  const unsigned short* qrow = qbf + ((size_t)bh*SEQ + q0 + ln)*DK;
  bf16x8 qf0 = *(const bf16x8*)(qrow + g*8);
  bf16x8 qf1 = *(const bf16x8*)(qrow + 32 + g*8);

  f32x4 o[4];
  #pragma unroll
  for (int f=0;f<4;f++) o[f] = (f32x4){0.f,0.f,0.f,0.f};
  float m_run = -1e30f, l_run = 0.f;

  const int sr = tid>>2, sc16 = (tid&3)*16;
  const unsigned short* ksrc = kbf + ((size_t)bh*SEQ + sr)*DK + sc16;
  const unsigned short* vsrc = vtg + ((size_t)bh*DK + sr)*SEQ + sc16;
  const int qg = q0 + ln;

  for (int t = 0; t <= qb; ++t) {
    const int kv0 = t*64;
    __syncthreads();
    { // stage K [64][64] and V^T [64][64]
      bf16x8 k0v = *(const bf16x8*)(ksrc + (size_t)kv0*DK);
      bf16x8 k1v = *(const bf16x8*)(ksrc + (size_t)kv0*DK + 8);
      bf16x8 v0v = *(const bf16x8*)(vsrc + kv0);
      bf16x8 v1v = *(const bf16x8*)(vsrc + kv0 + 8);
      *(bf16x8*)&Kt[sr][sc16]   = k0v;
      *(bf16x8*)&Kt[sr][sc16+8] = k1v;
      *(bf16x8*)&Vt[sr][sc16]   = v0v;
      *(bf16x8*)&Vt[sr][sc16+8] = v1v;
    }
    __syncthreads();

    // scores: S^T tile = mfma(K, Q): lane holds S[q=ln][kv=16*kvf+4g+j]
    f32x4 sa[4];
    #pragma unroll
    for (int kvf=0;kvf<4;kvf++) {
      f32x4 z = (f32x4){0.f,0.f,0.f,0.f};
      bf16x8 kf0 = *(const bf16x8*)&Kt[kvf*16 + ln][g*8];
      bf16x8 kf1 = *(const bf16x8*)&Kt[kvf*16 + ln][32 + g*8];
      z = mfma16(kf0, qf0, z);
      z = mfma16(kf1, qf1, z);
      sa[kvf] = z;
    }

    float sc[4][4];
    float lmax = -1e30f;
    if (t == qb) {
      #pragma unroll
      for (int kvf=0;kvf<4;kvf++)
        #pragma unroll
        for (int j=0;j<4;j++) {
          int kv = kv0 + kvf*16 + g*4 + j;
          float v = (kv <= qg) ? sa[kvf][j] : -1e30f;
          sc[kvf][j] = v; lmax = fmaxf(lmax, v);
        }
    } else {
      #pragma unroll
      for (int kvf=0;kvf<4;kvf++)
        #pragma unroll
        for (int j=0;j<4;j++) {
          float v = sa[kvf][j];
          sc[kvf][j] = v; lmax = fmaxf(lmax, v);
        }
    }
    lmax = fmaxf(lmax, __shfl_xor(lmax, 16));
    lmax = fmaxf(lmax, __shfl_xor(lmax, 32));

    // defer-max (T13): only rescale when a row grew by > 8 in exp2 domain
    if (!__all(lmax - m_run <= 8.0f)) {
      float mnew = fmaxf(m_run, lmax);
      float corr = exp2f(m_run - mnew);
      l_run *= corr;
      #pragma unroll
      for (int j=0;j<4;j++) {
        float cj = __shfl(corr, g*4 + j);
        #pragma unroll
        for (int f=0;f<4;f++) o[f][j] *= cj;
      }
      m_run = mnew;
    }

    float lsum = 0.f;
    #pragma unroll
    for (int kvf=0;kvf<4;kvf++) {
      float p0 = exp2f(sc[kvf][0] - m_run);
      float p1 = exp2f(sc[kvf][1] - m_run);
      float p2 = exp2f(sc[kvf][2] - m_run);
      float p3 = exp2f(sc[kvf][3] - m_run);
      lsum += (p0+p1)+(p2+p3);
      uint2 pk;
      pk.x = cvt_pk_bf16(p0, p1);
      pk.y = cvt_pk_bf16(p2, p3);
      *(uint2*)&Pl[w][ln][kvf*16 + g*4] = pk;
    }
    lsum += __shfl_xor(lsum, 16);
    lsum += __shfl_xor(lsum, 32);
    l_run += lsum;

    asm volatile("s_waitcnt lgkmcnt(0)" ::: "memory");  // P writes -> reads

    #pragma unroll
    for (int c=0;c<2;c++) {
      bf16x8 pf = *(const bf16x8*)&Pl[w][ln][c*32 + g*8];
      #pragma unroll
      for (int f=0;f<4;f++) {
        bf16x8 vf = *(const bf16x8*)&Vt[f*16 + ln][c*32 + g*8];
        o[f] = mfma16(pf, vf, o[f]);
      }
    }
  }

  const int bb = bh>>4, h = bh&15;
  #pragma unroll
  for (int j=0;j<4;j++) {
    float linv = 1.0f / __shfl(l_run, g*4 + j);
    int s = q0 + g*4 + j;
    #pragma unroll
    for (int f=0;f<4;f++)
      attnbf[((size_t)bb*SEQ + s)*DM + h*DK + f*16 + ln] = f2bf(o[f][j]*linv);
  }
}

// ---------------- launch ----------------
extern "C" void kernel_launch(void* const* d_in, const int* in_sizes, int n_in,
                              void* d_out, int out_size, void* d_ws, size_t ws_size,
                              hipStream_t stream)
{
  const float* x  = (const float*)d_in[0];
  const float* wq = (const float*)d_in[1];
  const float* wk = (const float*)d_in[2];
  const float* wv = (const float*)d_in[3];
  const float* wo = (const float*)d_in[4];
  const int*   tp = (const int*)d_in[5];

  const size_t XB = (size_t)BATCH*SEQ*DM*2;   // 16 MiB bf16 activation buffer
  const size_t WB = (size_t)DM*DM*2;          // 2 MiB bf16 weight
  const int    NW = DM*DM;

  char* ws = (char*)d_ws;
  unsigned short* xbf = (unsigned short*)(ws);
  unsigned short* qbf = (unsigned short*)(ws + XB);
  unsigned short* kbf = (unsigned short*)(ws + 2*XB);
  unsigned short* vt  = (unsigned short*)(ws + 3*XB);
  unsigned short* abf = (unsigned short*)(ws + 4*XB);
  unsigned short* wbf = (unsigned short*)(ws + 5*XB);
  float2* tab = (float2*)(ws + 5*XB + 4*WB);

  prep_kernel<<<12544, 256, 0, stream>>>(x, wq, wk, wv, wo, tp, xbf, wbf, tab);

  // fused Q/K/V projections (rope + Q pre-scale + V transpose in epilogue)
  gemm_qkv<<<dim3(24,64), 256, 0, stream>>>(xbf, wbf, qbf, kbf, vt, tab);
  // attention
  attn_fa<<<dim3(64,32), 256, 0, stream>>>(qbf, kbf, vt, abf);
  // output projection -> fp32 d_out
  gemm_ot<<<dim3(8,64), 256, 0, stream>>>(abf, wbf + 3*NW, nullptr != nullptr ? nullptr : (float*)d_out);
}

// Round 3
// 179.639 us; speedup vs baseline: 1.2707x; 1.1384x over previous
//
#include <hip/hip_runtime.h>
#include <hip/hip_bf16.h>
#include <stdint.h>

#define DM   1024
#define SEQ  2048
#define BATCH 4
#define NH   16
#define DK   64
#define NTK  16    // K=1024 / BK=64

typedef __attribute__((ext_vector_type(8))) __bf16 bf16x8;
typedef __attribute__((ext_vector_type(4))) float f32x4;
typedef __attribute__((ext_vector_type(4))) unsigned short ushort4_t;

typedef __attribute__((address_space(1))) const unsigned int GU32;
typedef __attribute__((address_space(3))) unsigned int LU32;

__device__ inline void gl_lds16(const void* g, void* l) {
  __builtin_amdgcn_global_load_lds((GU32*)g, (LU32*)l, 16, 0, 0);
}

__device__ inline f32x4 mfma16(bf16x8 a, bf16x8 b, f32x4 c) {
  return __builtin_amdgcn_mfma_f32_16x16x32_bf16(a, b, c, 0, 0, 0);
}

__device__ inline unsigned short f2bf(float f) {
  unsigned u = __float_as_uint(f);
  u += 0x7fffu + ((u >> 16) & 1u);
  return (unsigned short)(u >> 16);
}

__device__ inline unsigned cvt_pk_bf16(float a, float b) {
  unsigned r;
  asm("v_cvt_pk_bf16_f32 %0, %1, %2" : "=v"(r) : "v"(a), "v"(b));
  return r;  // lo = bf16(a), hi = bf16(b)
}

// col-chunk swizzle: spreads row-major [128][64] bf16 tile over all 32 banks
// for the 16-lane-per-column-group ds_read_b128 pattern.
__device__ inline int swz_of(int r) { return ((r & 6) << 2) | ((r & 1) << 5); }

// ---------------- prep: fp32 -> bf16 conversions + rope table ----------------
__global__ void prep_kernel(const float* __restrict__ x,
                            const float* __restrict__ wq, const float* __restrict__ wk,
                            const float* __restrict__ wv, const float* __restrict__ wo,
                            const int* __restrict__ tp,
                            unsigned short* __restrict__ xbf,
                            unsigned short* __restrict__ wbf,   // 4 weights contiguous
                            float2* __restrict__ tab)
{
  const int NX4 = (BATCH*SEQ*DM)/4;   // 2097152
  const int NW4 = (DM*DM)/4;          // 262144 = 2^18
  int idx = blockIdx.x*256 + threadIdx.x;
  if (idx < NX4) {
    float4 v = ((const float4*)x)[idx];
    ushort4_t o; o[0]=f2bf(v.x); o[1]=f2bf(v.y); o[2]=f2bf(v.z); o[3]=f2bf(v.w);
    ((ushort4_t*)xbf)[idx] = o;
  } else if (idx < NX4 + 4*NW4) {
    int t = idx - NX4;
    int wsel = t >> 18;
    int off = t & (NW4-1);
    const float* src = (wsel==0) ? wq : (wsel==1) ? wk : (wsel==2) ? wv : wo;
    float4 v = ((const float4*)src)[off];
    ushort4_t o; o[0]=f2bf(v.x); o[1]=f2bf(v.y); o[2]=f2bf(v.z); o[3]=f2bf(v.w);
    ((ushort4_t*)wbf)[wsel*NW4 + off] = o;
  } else {
    int t = idx - NX4 - 4*NW4;
    if (t < SEQ*32) {
      int s = t >> 5, i = t & 31;
      float invf = exp2f(-(float)i * (13.287712379549449f/32.0f));
      float ang = (float)tp[s] * invf;
      float sn, cs; sincosf(ang, &sn, &cs);
      tab[t] = make_float2(cs, sn);
    }
  }
}

// ---------------- GEMM: counted-vmcnt double-buffered 128x128, BK=64 ---------
// MODE 0: fused QKV (grid 1536 = 3 sel x 512); sel0: rope+scale->q, sel1: rope->k,
//         sel2: transpose->v^T.  MODE 1: O-proj (grid 512) -> fp32 d_out.
template<int MODE>
__global__ __launch_bounds__(256, 2)
void gemm_db(const unsigned short* __restrict__ A,
             const unsigned short* __restrict__ Wall,
             unsigned short* __restrict__ qbf,
             unsigned short* __restrict__ kbf,
             unsigned short* __restrict__ vt,
             float* __restrict__ ofp,
             const float2* __restrict__ tab)
{
  __shared__ __align__(16) char lds[65536];   // 2 slots x (A 16KB + B 16KB)
  const int tid = threadIdx.x;
  const int bid = blockIdx.x;
  int sel, mt, nt;
  if (MODE == 0) {
    sel = bid >> 9;
    int r = bid & 511;
    int xcd = r & 7, idx = r >> 3;          // per-XCD chunk: 8m x 8n, n inner
    mt = xcd*8 + (idx >> 3);  nt = idx & 7;
  } else {
    sel = 3;
    int xcd = bid & 7, idx = bid >> 3;      // 512 blocks: 8m x 8n per XCD
    mt = xcd*8 + (idx >> 3);  nt = idx & 7;
  }
  const unsigned short* Bm = Wall + (size_t)sel*DM*DM;
  const int a0 = mt*128, b0r = nt*128;
  const int w = tid>>6, lane = tid&63, ln = lane&15, g = lane>>4;
  const int wm = (w>>1)*64, wn = (w&1)*64;

  // ---- staging source pointers (pre-swizzled cols), i=0..3 A, 4..7 B ----
  const char* src[8];
  {
    int rr = tid >> 3;              // 0..31 (row within 32-row load round)
    int c  = (tid & 7) * 8;         // 0..56
    #pragma unroll
    for (int i = 0; i < 4; ++i) {
      int r_ = i*32 + rr;
      int cs = c ^ swz_of(r_);
      src[i]   = (const char*)(A  + (size_t)(a0  + r_)*DM + cs);
      src[i+4] = (const char*)(Bm + (size_t)(b0r + r_)*DM + cs);
    }
  }

  // ---- per-lane swizzled ds_read byte offsets (h=1 is ^64) ----
  int offA[4], offB[4];
  #pragma unroll
  for (int m = 0; m < 4; ++m) {
    int R  = wm + m*16 + ln;
    offA[m] = R*128 + ((g*8 ^ swz_of(R)) * 2);
    int Rb = wn + m*16 + ln;
    offB[m] = 16384 + Rb*128 + ((g*8 ^ swz_of(Rb)) * 2);
  }

  f32x4 acc[4][4];
  #pragma unroll
  for (int i=0;i<4;i++)
    #pragma unroll
    for (int j=0;j<4;j++) acc[i][j] = (f32x4){0.f,0.f,0.f,0.f};

  // ---- prologue: stage K0 -> slot0, K1 -> slot1 ----
  #pragma unroll
  for (int i = 0; i < 8; ++i) gl_lds16(src[i],       lds +         i*4096 + tid*16);
  #pragma unroll
  for (int i = 0; i < 8; ++i) gl_lds16(src[i] + 128, lds + 32768 + i*4096 + tid*16);

  // ---- main loop: counted vmcnt, prefetch depth 2 ----
  for (int t = 0; t < NTK; ++t) {
    char* sb = lds + (t & 1) * 32768;
    if (t < NTK-1) asm volatile("s_waitcnt vmcnt(8)" ::: "memory");
    else           asm volatile("s_waitcnt vmcnt(0)" ::: "memory");
    __builtin_amdgcn_sched_barrier(0);
    __builtin_amdgcn_s_barrier();          // all waves' K_t staging landed
    asm volatile("" ::: "memory");
    __builtin_amdgcn_sched_barrier(0);

    bf16x8 fa[4][2], fb[4][2];
    #pragma unroll
    for (int m = 0; m < 4; ++m) {
      fa[m][0] = *(const bf16x8*)(sb + offA[m]);
      fa[m][1] = *(const bf16x8*)(sb + (offA[m] ^ 64));
      fb[m][0] = *(const bf16x8*)(sb + offB[m]);
      fb[m][1] = *(const bf16x8*)(sb + (offB[m] ^ 64));
    }
    asm volatile("s_waitcnt lgkmcnt(0)" ::: "memory");
    __builtin_amdgcn_sched_barrier(0);
    __builtin_amdgcn_s_barrier();          // all waves done reading slot
    asm volatile("" ::: "memory");
    __builtin_amdgcn_sched_barrier(0);

    if (t + 2 < NTK) {                     // overwrite current slot with K_{t+2}
      const int kb = (t + 2) * 128;
      #pragma unroll
      for (int i = 0; i < 8; ++i)
        gl_lds16(src[i] + kb, sb + i*4096 + tid*16);
    }
    __builtin_amdgcn_s_setprio(1);
    #pragma unroll
    for (int h = 0; h < 2; ++h)
      #pragma unroll
      for (int m = 0; m < 4; ++m)
        #pragma unroll
        for (int n = 0; n < 4; ++n)
          acc[m][n] = mfma16(fa[m][h], fb[n][h], acc[m][n]);
    __builtin_amdgcn_s_setprio(0);
  }

  // ---- epilogues (verified in rounds 1-2) ----
  if (MODE == 1) {
    #pragma unroll
    for (int i=0;i<4;i++) {
      int m = a0 + wm + i*16 + g*4;
      #pragma unroll
      for (int jn=0;jn<4;jn++) {
        int n = b0r + wn + jn*16 + ln;
        #pragma unroll
        for (int j=0;j<4;j++)
          ofp[(size_t)(m+j)*DM + n] = acc[i][jn][j];
      }
    }
  } else if (sel == 2) {
    // transpose -> v^T [b,h,d,s]
    #pragma unroll
    for (int i=0;i<4;i++) {
      int m0 = a0 + wm + i*16 + g*4;
      int bb = m0>>11, s0 = m0&2047;
      #pragma unroll
      for (int jn=0;jn<4;jn++) {
        int n = b0r + wn + jn*16 + ln;
        int h = n>>6, d = n&63;
        ushort4_t o4;
        #pragma unroll
        for (int j=0;j<4;j++) o4[j] = f2bf(acc[i][jn][j]);
        *(ushort4_t*)&vt[(((size_t)bb*NH + h)*DK + d)*SEQ + s0] = o4;
      }
    }
  } else {
    unsigned short* dst = sel ? kbf : qbf;
    const float qs = sel ? 1.0f : 0.1803368802f;   // 1/8 * log2(e) folded into Q
    #pragma unroll
    for (int jn=0;jn<4;jn++) {
      int n = b0r + wn + jn*16 + ln;
      int h = n>>6, d = n&63, di = d>>1, par = d&1;
      #pragma unroll
      for (int i=0;i<4;i++) {
        #pragma unroll
        for (int j=0;j<4;j++) {
          int m = a0 + wm + i*16 + g*4 + j;
          int bb = m>>11, s = m&2047;
          float v = acc[i][jn][j];
          float pv = __shfl_xor(v, 1);
          float2 cssn = tab[s*32 + di];
          float r = par ? (v*cssn.x + pv*cssn.y) : (v*cssn.x - pv*cssn.y);
          dst[((size_t)(bb*NH + h)*SEQ + s)*DK + d] = f2bf(r*qs);
        }
      }
    }
  }
}

// ---------------- flash attention (unchanged from round 2) ----------------
__global__ __launch_bounds__(256, 2)
void attn_fa(const unsigned short* __restrict__ qbf,
             const unsigned short* __restrict__ kbf,
             const unsigned short* __restrict__ vtg,
             unsigned short* __restrict__ attnbf)
{
  __shared__ unsigned short Kt[64][72];
  __shared__ unsigned short Vt[64][72];
  __shared__ unsigned short Pl[4][16][72];
  const int bh = blockIdx.x, qb = 31 - blockIdx.y;
  const int tid = threadIdx.x, w = tid>>6, lane = tid&63, ln = lane&15, g = lane>>4;
  const int q0 = qb*64 + w*16;

  const unsigned short* qrow = qbf + ((size_t)bh*SEQ + q0 + ln)*DK;
  bf16x8 qf0 = *(const bf16x8*)(qrow + g*8);
  bf16x8 qf1 = *(const bf16x8*)(qrow + 32 + g*8);

  f32x4 o[4];
  #pragma unroll
  for (int f=0;f<4;f++) o[f] = (f32x4){0.f,0.f,0.f,0.f};
  float m_run = -1e30f, l_run = 0.f;

  const int sr = tid>>2, sc16 = (tid&3)*16;
  const unsigned short* ksrc = kbf + ((size_t)bh*SEQ + sr)*DK + sc16;
  const unsigned short* vsrc = vtg + ((size_t)bh*DK + sr)*SEQ + sc16;
  const int qg = q0 + ln;

  for (int t = 0; t <= qb; ++t) {
    const int kv0 = t*64;
    __syncthreads();
    {
      bf16x8 k0v = *(const bf16x8*)(ksrc + (size_t)kv0*DK);
      bf16x8 k1v = *(const bf16x8*)(ksrc + (size_t)kv0*DK + 8);
      bf16x8 v0v = *(const bf16x8*)(vsrc + kv0);
      bf16x8 v1v = *(const bf16x8*)(vsrc + kv0 + 8);
      *(bf16x8*)&Kt[sr][sc16]   = k0v;
      *(bf16x8*)&Kt[sr][sc16+8] = k1v;
      *(bf16x8*)&Vt[sr][sc16]   = v0v;
      *(bf16x8*)&Vt[sr][sc16+8] = v1v;
    }
    __syncthreads();

    f32x4 sa[4];
    #pragma unroll
    for (int kvf=0;kvf<4;kvf++) {
      f32x4 z = (f32x4){0.f,0.f,0.f,0.f};
      bf16x8 kf0 = *(const bf16x8*)&Kt[kvf*16 + ln][g*8];
      bf16x8 kf1 = *(const bf16x8*)&Kt[kvf*16 + ln][32 + g*8];
      z = mfma16(kf0, qf0, z);
      z = mfma16(kf1, qf1, z);
      sa[kvf] = z;
    }

    float sc[4][4];
    float lmax = -1e30f;
    if (t == qb) {
      #pragma unroll
      for (int kvf=0;kvf<4;kvf++)
        #pragma unroll
        for (int j=0;j<4;j++) {
          int kv = kv0 + kvf*16 + g*4 + j;
          float v = (kv <= qg) ? sa[kvf][j] : -1e30f;
          sc[kvf][j] = v; lmax = fmaxf(lmax, v);
        }
    } else {
      #pragma unroll
      for (int kvf=0;kvf<4;kvf++)
        #pragma unroll
        for (int j=0;j<4;j++) {
          float v = sa[kvf][j];
          sc[kvf][j] = v; lmax = fmaxf(lmax, v);
        }
    }
    lmax = fmaxf(lmax, __shfl_xor(lmax, 16));
    lmax = fmaxf(lmax, __shfl_xor(lmax, 32));

    if (!__all(lmax - m_run <= 8.0f)) {
      float mnew = fmaxf(m_run, lmax);
      float corr = exp2f(m_run - mnew);
      l_run *= corr;
      #pragma unroll
      for (int j=0;j<4;j++) {
        float cj = __shfl(corr, g*4 + j);
        #pragma unroll
        for (int f=0;f<4;f++) o[f][j] *= cj;
      }
      m_run = mnew;
    }

    float lsum = 0.f;
    #pragma unroll
    for (int kvf=0;kvf<4;kvf++) {
      float p0 = exp2f(sc[kvf][0] - m_run);
      float p1 = exp2f(sc[kvf][1] - m_run);
      float p2 = exp2f(sc[kvf][2] - m_run);
      float p3 = exp2f(sc[kvf][3] - m_run);
      lsum += (p0+p1)+(p2+p3);
      uint2 pk;
      pk.x = cvt_pk_bf16(p0, p1);
      pk.y = cvt_pk_bf16(p2, p3);
      *(uint2*)&Pl[w][ln][kvf*16 + g*4] = pk;
    }
    lsum += __shfl_xor(lsum, 16);
    lsum += __shfl_xor(lsum, 32);
    l_run += lsum;

    asm volatile("s_waitcnt lgkmcnt(0)" ::: "memory");

    #pragma unroll
    for (int c=0;c<2;c++) {
      bf16x8 pf = *(const bf16x8*)&Pl[w][ln][c*32 + g*8];
      #pragma unroll
      for (int f=0;f<4;f++) {
        bf16x8 vf = *(const bf16x8*)&Vt[f*16 + ln][c*32 + g*8];
        o[f] = mfma16(pf, vf, o[f]);
      }
    }
  }

  const int bb = bh>>4, h = bh&15;
  #pragma unroll
  for (int j=0;j<4;j++) {
    float linv = 1.0f / __shfl(l_run, g*4 + j);
    int s = q0 + g*4 + j;
    #pragma unroll
    for (int f=0;f<4;f++)
      attnbf[((size_t)bb*SEQ + s)*DM + h*DK + f*16 + ln] = f2bf(o[f][j]*linv);
  }
}

// ---------------- launch ----------------
extern "C" void kernel_launch(void* const* d_in, const int* in_sizes, int n_in,
                              void* d_out, int out_size, void* d_ws, size_t ws_size,
                              hipStream_t stream)
{
  const float* x  = (const float*)d_in[0];
  const float* wq = (const float*)d_in[1];
  const float* wk = (const float*)d_in[2];
  const float* wv = (const float*)d_in[3];
  const float* wo = (const float*)d_in[4];
  const int*   tp = (const int*)d_in[5];

  const size_t XB = (size_t)BATCH*SEQ*DM*2;   // 16 MiB bf16 activation buffer
  const size_t WB = (size_t)DM*DM*2;          // 2 MiB bf16 weight

  char* ws = (char*)d_ws;
  unsigned short* xbf = (unsigned short*)(ws);
  unsigned short* qbf = (unsigned short*)(ws + XB);
  unsigned short* kbf = (unsigned short*)(ws + 2*XB);
  unsigned short* vt  = (unsigned short*)(ws + 3*XB);
  unsigned short* abf = (unsigned short*)(ws + 4*XB);
  unsigned short* wbf = (unsigned short*)(ws + 5*XB);
  float2* tab = (float2*)(ws + 5*XB + 4*WB);

  prep_kernel<<<12544, 256, 0, stream>>>(x, wq, wk, wv, wo, tp, xbf, wbf, tab);

  // fused Q/K/V projections: sel-major, XCD-chunked
  gemm_db<0><<<1536, 256, 0, stream>>>(xbf, wbf, qbf, kbf, vt, nullptr, tab);
  // attention
  attn_fa<<<dim3(64,32), 256, 0, stream>>>(qbf, kbf, vt, abf);
  // output projection -> fp32 d_out
  gemm_db<1><<<512, 256, 0, stream>>>(abf, wbf, nullptr, nullptr, nullptr,
                                      (float*)d_out, nullptr);
}